// Round 6
// baseline (147.145 us; speedup 1.0000x reference)
//
#include <hip/hip_runtime.h>
#include <math.h>

typedef _Float16 f16;
typedef __attribute__((ext_vector_type(8))) _Float16 f16x8;
typedef __attribute__((ext_vector_type(4))) _Float16 f16x4;
typedef __attribute__((ext_vector_type(4))) float f32x4;
typedef __attribute__((ext_vector_type(16))) float f32x16;

#define MFMA16(a, b, c) __builtin_amdgcn_mfma_f32_16x16x32_f16((a), (b), (c), 0, 0, 0)
#define MFMA32(a, b, c) __builtin_amdgcn_mfma_f32_32x32x16_f16((a), (b), (c), 0, 0, 0)

__device__ __forceinline__ void gld16(const f16* g, f16* l) {
  __builtin_amdgcn_global_load_lds(
      (const __attribute__((address_space(1))) unsigned int*)g,
      (__attribute__((address_space(3))) unsigned int*)l, 16, 0, 0);
}

__device__ __forceinline__ f16x8 pack8(const float* src) {
  float4 f0 = *(const float4*)src;
  float4 f1 = *(const float4*)(src + 4);
  f16x8 v;
  v[0] = (f16)f0.x; v[1] = (f16)f0.y; v[2] = (f16)f0.z; v[3] = (f16)f0.w;
  v[4] = (f16)f1.x; v[5] = (f16)f1.y; v[6] = (f16)f1.z; v[7] = (f16)f1.w;
  return v;
}

// ---------------- prep: cast weights to f16 ----------------
__global__ __launch_bounds__(256) void prep_w(const float* __restrict__ wq,
                                              const float* __restrict__ wk,
                                              const float* __restrict__ wv,
                                              const float* __restrict__ wp,
                                              f16* __restrict__ wqkvb,
                                              f16* __restrict__ wpb) {
  int i = blockIdx.x * 256 + threadIdx.x;  // grid = 128 -> i in [0, 32768)
  wqkvb[i] = (f16)wk[i];
  wqkvb[32768 + i] = (f16)wv[i];
  wqkvb[65536 + i] = (f16)wq[i];
  wpb[i] = (f16)wp[i];
}

// ---------------- k1_qkv: sigQ[m][h], XT[b*128+h][t]=eK*V, XT[b*128+64+h][t]=eK --------
__global__ __launch_bounds__(256) void k1_qkv(const float* __restrict__ x,
                                              const f16* __restrict__ wqkvb,
                                              const float* __restrict__ bq,
                                              const float* __restrict__ bk,
                                              const float* __restrict__ bv,
                                              f16* __restrict__ sigQ,
                                              f16* __restrict__ XT) {
  __shared__ alignas(16) f16 sW[192 * 64];
  __shared__ alignas(16) f16 sX[64 * 64];
  const int tid = threadIdx.x;
  const int wave = tid >> 6, lane = tid & 63;
  const int m0 = blockIdx.x * 64;
  const int l15 = lane & 15;

  f32x4 accQ[4], accK[4], accV[4];
#pragma unroll
  for (int j = 0; j < 4; ++j) {
    accQ[j] = (f32x4){0.f, 0.f, 0.f, 0.f};
    accK[j] = (f32x4){0.f, 0.f, 0.f, 0.f};
    accV[j] = (f32x4){0.f, 0.f, 0.f, 0.f};
  }

  const int sc8 = tid & 7;
  const int wr8 = (tid >> 3) & 7;
  const int wcol = (sc8 ^ wr8) * 8;

  for (int ks = 0; ks < 512; ks += 64) {
#pragma unroll
    for (int q = 0; q < 6; ++q) {
      int r = q * 32 + (tid >> 3);
      gld16(wqkvb + (size_t)r * 512 + ks + wcol, &sW[r * 64 + sc8 * 8]);
    }
#pragma unroll
    for (int u = 0; u < 2; ++u) {
      int un = tid + u * 256;
      int r = un >> 3, c8 = un & 7;
      *(f16x8*)&sX[r * 64 + ((c8 ^ (r & 7)) * 8)] =
          pack8(x + (size_t)(m0 + r) * 512 + ks + c8 * 8);
    }
    __syncthreads();
#pragma unroll
    for (int kk = 0; kk < 2; ++kk) {
      const int c = kk * 4 + (lane >> 4);
      const int rK = wave * 16 + l15;
      const int rV = 64 + rK;
      f16x8 aK = *(const f16x8*)&sW[rK * 64 + ((c ^ (rK & 7)) * 8)];
      f16x8 aV = *(const f16x8*)&sW[rV * 64 + ((c ^ (rV & 7)) * 8)];
      f16x8 aQ = *(const f16x8*)&sX[rK * 64 + ((c ^ (rK & 7)) * 8)];
#pragma unroll
      for (int j = 0; j < 4; ++j) {
        const int rX = j * 16 + l15;
        const int rWq = 128 + j * 16 + l15;
        f16x8 bx = *(const f16x8*)&sX[rX * 64 + ((c ^ (rX & 7)) * 8)];
        f16x8 bw = *(const f16x8*)&sW[rWq * 64 + ((c ^ (rWq & 7)) * 8)];
        accK[j] = MFMA16(aK, bx, accK[j]);
        accV[j] = MFMA16(aV, bx, accV[j]);
        accQ[j] = MFMA16(aQ, bw, accQ[j]);
      }
    }
    __syncthreads();
  }
  const int b = m0 >> 12, t0 = m0 & 4095;
#pragma unroll
  for (int j = 0; j < 4; ++j) {
    const int h = j * 16 + l15;
    const float bqv = bq[h];
#pragma unroll
    for (int r = 0; r < 4; ++r) {
      const int m = m0 + wave * 16 + (lane >> 4) * 4 + r;
      const float v = accQ[j][r] + bqv;
      sigQ[(size_t)m * 64 + h] = (f16)(1.f / (1.f + expf(-v)));
    }
  }
#pragma unroll
  for (int r = 0; r < 4; ++r) {
    const int h = wave * 16 + (lane >> 4) * 4 + r;
    const float bkv = bk[h], bvv = bv[h];
    const size_t rowKV = (size_t)(b * 128 + h) * 4096;
    const size_t rowK = (size_t)(b * 128 + 64 + h) * 4096;
#pragma unroll
    for (int j = 0; j < 4; ++j) {
      const int t = t0 + j * 16 + l15;
      const float ek = expf(accK[j][r] + bkv);
      const float ev = accV[j][r] + bvv;
      XT[rowKV + t] = (f16)(ek * ev);
      XT[rowK + t] = (f16)ek;
    }
  }
}

// ---------------- k2_big: Yt = sigQ * (exp(wbias)@num^T)/(exp(wbias)@den^T) --------
// R3-proven structure (2-phase counted-prefetch, BK=128, K-split-2, 64x64 wave
// tiles, XOR-16 swizzle, XCD-aware bid map) with exp(wbias) FUSED into the
// A-staging: A is reg-staged from f32 wbias (T14 issue-early/write-late),
// exp+cvt+swizzled ds_write hide in the measured per-tile stall. B stays on
// the gld16 DMA path. prep_ew kernel deleted.
__global__ __launch_bounds__(512) void k2_big(const float* __restrict__ Ap,
                                              const f16* __restrict__ Bm,
                                              const f16* __restrict__ sigQ,
                                              f16* __restrict__ Yt) {
  __shared__ alignas(16) f16 sA[2][128 * 128];
  __shared__ alignas(16) f16 sB[2][128 * 128];
  const int tid = threadIdx.x;
  const int wave = tid >> 6, lane = tid & 63;
  const int kh = wave >> 2;            // k-half
  const int wq = wave & 3;
  const int wr = wq >> 1, wc = wq & 1;
  const int bid = blockIdx.x;
  const int b = (bid >> 3) & 7;
  const int m0 = ((bid & 7) + 8 * (bid >> 6)) * 128;  // same-m blocks share XCD
  const f16* Bb = Bm + (size_t)(b * 128) * 4096;

  const int srow = tid >> 4;           // 0..31 (B staging)
  const int sc16 = tid & 15;
  const int gcol = (sc16 ^ (srow & 15)) * 8;  // pre-swizzled source col (XOR-16)

  const int ar = tid >> 2;             // A staging: row 0..127
  const int ac = (tid & 3) * 32;       // 32 contiguous cols per thread

  f32x16 acc[2][2];
#pragma unroll
  for (int i = 0; i < 2; ++i)
#pragma unroll
    for (int j = 0; j < 2; ++j)
#pragma unroll
      for (int r = 0; r < 16; ++r) acc[i][j][r] = 0.f;

  float4 An[8];

#define K2_LOADA(ks)                                                            \
  do {                                                                          \
    const float* ap = Ap + (size_t)(m0 + ar) * 4096 + (ks) + ac;                \
    _Pragma("unroll") for (int q = 0; q < 8; ++q) An[q] = *(const float4*)(ap + q * 4); \
  } while (0)

#define K2_WRITEA(buf)                                                          \
  do {                                                                          \
    _Pragma("unroll") for (int h = 0; h < 4; ++h) {                             \
      f16x8 v;                                                                  \
      v[0] = (f16)__expf(An[2 * h].x);                                          \
      v[1] = (f16)__expf(An[2 * h].y);                                          \
      v[2] = (f16)__expf(An[2 * h].z);                                          \
      v[3] = (f16)__expf(An[2 * h].w);                                          \
      v[4] = (f16)__expf(An[2 * h + 1].x);                                      \
      v[5] = (f16)__expf(An[2 * h + 1].y);                                      \
      v[6] = (f16)__expf(An[2 * h + 1].z);                                      \
      v[7] = (f16)__expf(An[2 * h + 1].w);                                      \
      const int c = (tid & 3) * 4 + h;                                          \
      *(f16x8*)&sA[buf][ar * 128 + ((c ^ (ar & 15)) * 8)] = v;                  \
    }                                                                           \
  } while (0)

#define K2_STAGEB(buf, ks)                                                      \
  do {                                                                          \
    _Pragma("unroll") for (int q = 0; q < 4; ++q) {                             \
      int r = q * 32 + srow;                                                    \
      gld16(Bb + (size_t)r * 4096 + (ks) + gcol, &sB[buf][r * 128 + sc16 * 8]); \
    }                                                                           \
  } while (0)

  // prologue: stage tiles 0 and 1; only B(1)'s DMA left in flight at the barrier
  K2_LOADA(0);
  K2_STAGEB(0, 0);
  K2_WRITEA(0);                         // implicit wait on A(0) loads
  K2_LOADA(128);
  K2_STAGEB(1, 128);
  K2_WRITEA(1);                         // implicit wait on A(1) ⇒ B(0) done (in-order)
  asm volatile("s_waitcnt vmcnt(4)" ::: "memory");
  asm volatile("s_waitcnt lgkmcnt(0)" ::: "memory");
  __builtin_amdgcn_sched_barrier(0);
  __builtin_amdgcn_s_barrier();

  const int rA0 = wr * 64 + (lane & 31);
  const int rB0 = wc * 32 + (lane & 31);
  const int l15x = lane & 15;
  const int nk = 32;
  for (int t = 0; t < nk; ++t) {
    const int cur = t & 1;
    if (t + 2 < nk) K2_LOADA((t + 2) * 128);  // issue early; lands under compute
    __builtin_amdgcn_sched_barrier(0);
#pragma unroll
    for (int kk = 0; kk < 4; ++kk) {
      const int c = kh * 8 + kk * 2 + (lane >> 5);
      const int cx = (c ^ l15x) * 8;
      f16x8 a0 = *(const f16x8*)&sA[cur][rA0 * 128 + cx];
      f16x8 a1 = *(const f16x8*)&sA[cur][(rA0 + 32) * 128 + cx];
      f16x8 b0 = *(const f16x8*)&sB[cur][rB0 * 128 + cx];
      f16x8 b1 = *(const f16x8*)&sB[cur][(rB0 + 64) * 128 + cx];
      acc[0][0] = MFMA32(a0, b0, acc[0][0]);
      acc[0][1] = MFMA32(a0, b1, acc[0][1]);
      acc[1][0] = MFMA32(a1, b0, acc[1][0]);
      acc[1][1] = MFMA32(a1, b1, acc[1][1]);
    }
    asm volatile("s_waitcnt lgkmcnt(0)" ::: "memory");
    __builtin_amdgcn_sched_barrier(0);
    __builtin_amdgcn_s_barrier();       // all waves done reading buf cur
    if (t + 2 < nk) {
      K2_STAGEB(cur, (t + 2) * 128);    // DMA tile t+2 B into cur
      __builtin_amdgcn_sched_barrier(0);
      K2_WRITEA(cur);                   // implicit wait A(t+2) ⇒ B(t+1) done; B(t+2) stays in flight
      asm volatile("s_waitcnt lgkmcnt(0)" ::: "memory");
    } else {
      asm volatile("s_waitcnt vmcnt(0)" ::: "memory");
    }
    __builtin_amdgcn_sched_barrier(0);
    __builtin_amdgcn_s_barrier();       // tile t+1 ready
  }
#undef K2_LOADA
#undef K2_WRITEA
#undef K2_STAGEB

  // merge k-halves through LDS (reuse sA region: 16 tiles x 4KB = 64KB)
  __syncthreads();
  float* red = (float*)sA;
  if (kh == 1) {
#pragma unroll
    for (int i = 0; i < 2; ++i)
#pragma unroll
      for (int j = 0; j < 2; ++j)
#pragma unroll
        for (int r = 0; r < 16; ++r)
          red[(((wq * 2 + i) * 2 + j) << 10) + (r << 6) + lane] = acc[i][j][r];
  }
  __syncthreads();
  if (kh == 0) {
#pragma unroll
    for (int i = 0; i < 2; ++i)
#pragma unroll
      for (int j = 0; j < 2; ++j)
#pragma unroll
        for (int r = 0; r < 16; ++r)
          acc[i][j][r] += red[(((wq * 2 + i) * 2 + j) << 10) + (r << 6) + lane];
    // fused epilogue: Yt = sigQ * num / den
    const int colh = wc * 32 + (lane & 31);
    const int rbase = (lane >> 5) * 4;
#pragma unroll
    for (int i = 0; i < 2; ++i) {
      const int tb = m0 + wr * 64 + i * 32;
#pragma unroll
      for (int r = 0; r < 16; ++r) {
        const int trow = tb + (r & 3) + 8 * (r >> 2) + rbase;
        const size_t mrow = (size_t)b * 4096 + trow;
        const float num = acc[i][0][r];
        const float den = acc[i][1][r];
        const float sq = (float)sigQ[mrow * 64 + colh];
        Yt[mrow * 64 + colh] = (f16)(sq * num / den);
      }
    }
  }
}

// ---------------- k4_out: out[m][d] = Yt @ wp^T + bp (f32 out) ----------------
__global__ __launch_bounds__(256) void k4_out(const f16* __restrict__ Yt,
                                              const f16* __restrict__ wpb,
                                              const float* __restrict__ bp,
                                              float* __restrict__ out) {
  __shared__ alignas(16) f16 sA[128 * 64];
  __shared__ alignas(16) f16 sB[128 * 64];
  const int tid = threadIdx.x;
  const int wave = tid >> 6, lane = tid & 63;
  const int m0 = blockIdx.x * 128;  // 256
  const int n0 = blockIdx.y * 128;  // 4
  const int wm = (wave >> 1) * 64;
  const int wn = (wave & 1) * 64;
  const int l15 = lane & 15;
  const int sc8 = tid & 7;
  const int scol = (sc8 ^ ((tid >> 3) & 7)) * 8;

#pragma unroll
  for (int q = 0; q < 4; ++q) {
    int r = q * 32 + (tid >> 3);
    gld16(Yt + (size_t)(m0 + r) * 64 + scol, &sA[r * 64 + sc8 * 8]);
    gld16(wpb + (size_t)(n0 + r) * 64 + scol, &sB[r * 64 + sc8 * 8]);
  }
  __syncthreads();

  f32x4 acc[4][4];
#pragma unroll
  for (int i = 0; i < 4; ++i)
#pragma unroll
    for (int j = 0; j < 4; ++j) acc[i][j] = (f32x4){0.f, 0.f, 0.f, 0.f};

#pragma unroll
  for (int kk = 0; kk < 2; ++kk) {
    const int c = kk * 4 + (lane >> 4);
    f16x8 af[4], bfr[4];
#pragma unroll
    for (int i = 0; i < 4; ++i) {
      const int r = wm + i * 16 + l15;
      af[i] = *(const f16x8*)&sA[r * 64 + ((c ^ (r & 7)) * 8)];
    }
#pragma unroll
    for (int j = 0; j < 4; ++j) {
      const int r = wn + j * 16 + l15;
      bfr[j] = *(const f16x8*)&sB[r * 64 + ((c ^ (r & 7)) * 8)];
    }
#pragma unroll
    for (int i = 0; i < 4; ++i)
#pragma unroll
      for (int j = 0; j < 4; ++j) acc[i][j] = MFMA16(af[i], bfr[j], acc[i][j]);
  }

#pragma unroll
  for (int i = 0; i < 4; ++i) {
    const int row = m0 + wm + i * 16 + (lane >> 4) * 4;
#pragma unroll
    for (int j = 0; j < 4; ++j) {
      const int col = n0 + wn + j * 16 + l15;
      const float bpv = bp[col];
#pragma unroll
      for (int r = 0; r < 4; ++r)
        out[(size_t)(row + r) * 512 + col] = acc[i][j][r] + bpv;
    }
  }
}

extern "C" void kernel_launch(void* const* d_in, const int* in_sizes, int n_in,
                              void* d_out, int out_size, void* d_ws, size_t ws_size,
                              hipStream_t stream) {
  const float* x = (const float*)d_in[0];
  const float* wq = (const float*)d_in[1];
  const float* bq = (const float*)d_in[2];
  const float* wk = (const float*)d_in[3];
  const float* bk = (const float*)d_in[4];
  const float* wv = (const float*)d_in[5];
  const float* bv = (const float*)d_in[6];
  const float* wp = (const float*)d_in[7];
  const float* bp = (const float*)d_in[8];
  const float* wbias = (const float*)d_in[9];
  float* out = (float*)d_out;

  char* ws = (char*)d_ws;
  f16* XT = (f16*)(ws);                  //  8,388,608 B
  f16* sigQ = (f16*)(ws + 8388608);      //  4,194,304 B
  f16* Yt = (f16*)(ws + 12582912);       //  4,194,304 B
  f16* wqkvb = (f16*)(ws + 16777216);    //    196,608 B
  f16* wpb = (f16*)(ws + 16973824);      //     65,536 B (end 17,039,360)

  prep_w<<<128, 256, 0, stream>>>(wq, wk, wv, wp, wqkvb, wpb);
  k1_qkv<<<512, 256, 0, stream>>>(x, wqkvb, bq, bk, bv, sigQ, XT);
  k2_big<<<256, 512, 0, stream>>>(wbias, XT, sigQ, Yt);
  k4_out<<<dim3(256, 4), 256, 0, stream>>>(Yt, wpb, bp, out);
}

// Round 7
// 105.677 us; speedup vs baseline: 1.3924x; 1.3924x over previous
//
#include <hip/hip_runtime.h>
#include <math.h>

typedef _Float16 f16;
typedef __attribute__((ext_vector_type(8))) _Float16 f16x8;
typedef __attribute__((ext_vector_type(4))) _Float16 f16x4;
typedef __attribute__((ext_vector_type(4))) float f32x4;
typedef __attribute__((ext_vector_type(16))) float f32x16;

#define MFMA16(a, b, c) __builtin_amdgcn_mfma_f32_16x16x32_f16((a), (b), (c), 0, 0, 0)
#define MFMA32(a, b, c) __builtin_amdgcn_mfma_f32_32x32x16_f16((a), (b), (c), 0, 0, 0)

__device__ __forceinline__ void gld16(const f16* g, f16* l) {
  __builtin_amdgcn_global_load_lds(
      (const __attribute__((address_space(1))) unsigned int*)g,
      (__attribute__((address_space(3))) unsigned int*)l, 16, 0, 0);
}

__device__ __forceinline__ f16x8 pack8(const float* src) {
  float4 f0 = *(const float4*)src;
  float4 f1 = *(const float4*)(src + 4);
  f16x8 v;
  v[0] = (f16)f0.x; v[1] = (f16)f0.y; v[2] = (f16)f0.z; v[3] = (f16)f0.w;
  v[4] = (f16)f1.x; v[5] = (f16)f1.y; v[6] = (f16)f1.z; v[7] = (f16)f1.w;
  return v;
}

// ---------------- prep: ew = exp(wbias) as f16 [4096][4096] ----------------
__global__ __launch_bounds__(256) void prep_ew(const float* __restrict__ wb,
                                               f16* __restrict__ ew) {
  const size_t stride = (size_t)gridDim.x * 256;
  const size_t total = (size_t)4096 * 4096 / 4;
  for (size_t i = (size_t)blockIdx.x * 256 + threadIdx.x; i < total; i += stride) {
    float4 f = ((const float4*)wb)[i];
    f16x4 o;
    o.x = (f16)expf(f.x); o.y = (f16)expf(f.y);
    o.z = (f16)expf(f.z); o.w = (f16)expf(f.w);
    ((f16x4*)ew)[i] = o;
  }
}

// ---------------- prep: cast weights to f16 ----------------
__global__ __launch_bounds__(256) void prep_w(const float* __restrict__ wq,
                                              const float* __restrict__ wk,
                                              const float* __restrict__ wv,
                                              const float* __restrict__ wp,
                                              f16* __restrict__ wqkvb,
                                              f16* __restrict__ wpb) {
  int i = blockIdx.x * 256 + threadIdx.x;  // grid = 128 -> i in [0, 32768)
  wqkvb[i] = (f16)wk[i];
  wqkvb[32768 + i] = (f16)wv[i];
  wqkvb[65536 + i] = (f16)wq[i];
  wpb[i] = (f16)wp[i];
}

// ---------------- k1_qkv: sigQ[m][h], XT[b*128+h][t]=eK*V, XT[b*128+64+h][t]=eK --------
__global__ __launch_bounds__(256) void k1_qkv(const float* __restrict__ x,
                                              const f16* __restrict__ wqkvb,
                                              const float* __restrict__ bq,
                                              const float* __restrict__ bk,
                                              const float* __restrict__ bv,
                                              f16* __restrict__ sigQ,
                                              f16* __restrict__ XT) {
  __shared__ alignas(16) f16 sW[192 * 64];
  __shared__ alignas(16) f16 sX[64 * 64];
  const int tid = threadIdx.x;
  const int wave = tid >> 6, lane = tid & 63;
  const int m0 = blockIdx.x * 64;
  const int l15 = lane & 15;

  f32x4 accQ[4], accK[4], accV[4];
#pragma unroll
  for (int j = 0; j < 4; ++j) {
    accQ[j] = (f32x4){0.f, 0.f, 0.f, 0.f};
    accK[j] = (f32x4){0.f, 0.f, 0.f, 0.f};
    accV[j] = (f32x4){0.f, 0.f, 0.f, 0.f};
  }

  const int sc8 = tid & 7;
  const int wr8 = (tid >> 3) & 7;
  const int wcol = (sc8 ^ wr8) * 8;

  for (int ks = 0; ks < 512; ks += 64) {
#pragma unroll
    for (int q = 0; q < 6; ++q) {
      int r = q * 32 + (tid >> 3);
      gld16(wqkvb + (size_t)r * 512 + ks + wcol, &sW[r * 64 + sc8 * 8]);
    }
#pragma unroll
    for (int u = 0; u < 2; ++u) {
      int un = tid + u * 256;
      int r = un >> 3, c8 = un & 7;
      *(f16x8*)&sX[r * 64 + ((c8 ^ (r & 7)) * 8)] =
          pack8(x + (size_t)(m0 + r) * 512 + ks + c8 * 8);
    }
    __syncthreads();
#pragma unroll
    for (int kk = 0; kk < 2; ++kk) {
      const int c = kk * 4 + (lane >> 4);
      const int rK = wave * 16 + l15;
      const int rV = 64 + rK;
      f16x8 aK = *(const f16x8*)&sW[rK * 64 + ((c ^ (rK & 7)) * 8)];
      f16x8 aV = *(const f16x8*)&sW[rV * 64 + ((c ^ (rV & 7)) * 8)];
      f16x8 aQ = *(const f16x8*)&sX[rK * 64 + ((c ^ (rK & 7)) * 8)];
#pragma unroll
      for (int j = 0; j < 4; ++j) {
        const int rX = j * 16 + l15;
        const int rWq = 128 + j * 16 + l15;
        f16x8 bx = *(const f16x8*)&sX[rX * 64 + ((c ^ (rX & 7)) * 8)];
        f16x8 bw = *(const f16x8*)&sW[rWq * 64 + ((c ^ (rWq & 7)) * 8)];
        accK[j] = MFMA16(aK, bx, accK[j]);
        accV[j] = MFMA16(aV, bx, accV[j]);
        accQ[j] = MFMA16(aQ, bw, accQ[j]);
      }
    }
    __syncthreads();
  }
  const int b = m0 >> 12, t0 = m0 & 4095;
#pragma unroll
  for (int j = 0; j < 4; ++j) {
    const int h = j * 16 + l15;
    const float bqv = bq[h];
#pragma unroll
    for (int r = 0; r < 4; ++r) {
      const int m = m0 + wave * 16 + (lane >> 4) * 4 + r;
      const float v = accQ[j][r] + bqv;
      sigQ[(size_t)m * 64 + h] = (f16)(1.f / (1.f + expf(-v)));
    }
  }
#pragma unroll
  for (int r = 0; r < 4; ++r) {
    const int h = wave * 16 + (lane >> 4) * 4 + r;
    const float bkv = bk[h], bvv = bv[h];
    const size_t rowKV = (size_t)(b * 128 + h) * 4096;
    const size_t rowK = (size_t)(b * 128 + 64 + h) * 4096;
#pragma unroll
    for (int j = 0; j < 4; ++j) {
      const int t = t0 + j * 16 + l15;
      const float ek = expf(accK[j][r] + bkv);
      const float ev = accV[j][r] + bvv;
      XT[rowKV + t] = (f16)(ek * ev);
      XT[rowK + t] = (f16)ek;
    }
  }
}

// ---------------- k2_big: Yt = sigQ * (ew@num^T)/(ew@den^T), fused ----------------
// BM=64, BN=128 (one batch: 64 num + 64 den), BK=64, 256 thr (4 waves), grid
// 512 = 2 blocks/CU (the occupancy lever). No K-split: wave (wr,wc) owns rows
// wr*32, matched num/den col pair wc*32+l31 -> in-register epilogue. LDS tiles
// packed as 128-f16-wide rows ([32][128], [64][128]) with XOR-16 both-sides
// swizzle + chunk-includes-lhi read geometry (R3-proven, 0 conflicts).
// Counted-vmcnt 2-phase schedule (vmcnt(6): 6 gld16/tile). XCD map: same-m
// blocks on one XCD (8 x 512KB ew panels = 4MB = L2).
__global__ __launch_bounds__(256) void k2_big(const f16* __restrict__ A,
                                              const f16* __restrict__ Bm,
                                              const f16* __restrict__ sigQ,
                                              f16* __restrict__ Yt) {
  __shared__ alignas(16) f16 sA[2][32 * 128];  // A tile 64x64 packed [32][128]
  __shared__ alignas(16) f16 sB[2][64 * 128];  // B tile 128x64 packed [64][128]
  const int tid = threadIdx.x;
  const int wave = tid >> 6, lane = tid & 63;
  const int wr = wave >> 1, wc = wave & 1;
  const int bid = blockIdx.x;
  const int b = (bid >> 3) & 7;
  const int m0 = ((bid & 7) + 8 * (bid >> 6)) * 64;  // same-m blocks share XCD
  const f16* Bb = Bm + (size_t)(b * 128) * 4096;

  // ---- staging address precompute (pre-swizzled global source, linear LDS dest)
  // A: 2 instrs, d = q*256+tid in [0,512): lrow=d>>4 (0..31), cc=d&15,
  //    oc=cc^(lrow&15) -> src row = lrow+32*(oc>>3), src chunk = oc&7.
  int aRow[2], aCol[2];
#pragma unroll
  for (int q = 0; q < 2; ++q) {
    int d = q * 256 + tid;
    int lrow = d >> 4, cc = d & 15;
    int oc = cc ^ (lrow & 15);
    aRow[q] = lrow + 32 * (oc >> 3);
    aCol[q] = (oc & 7) * 8;
  }
  // B: 4 instrs, d = q*256+tid in [0,1024): lrow=d>>4 (0..63), cc=d&15,
  //    oc=cc^(lrow&15) -> src row = lrow+64*(oc>>3), src chunk = oc&7.
  int bRow[4], bCol[4];
#pragma unroll
  for (int q = 0; q < 4; ++q) {
    int d = q * 256 + tid;
    int lrow = d >> 4, cc = d & 15;
    int oc = cc ^ (lrow & 15);
    bRow[q] = lrow + 64 * (oc >> 3);
    bCol[q] = (oc & 7) * 8;
  }

  f32x16 accN, accD;
#pragma unroll
  for (int r = 0; r < 16; ++r) { accN[r] = 0.f; accD[r] = 0.f; }

#define K2_STAGE(buf, ks)                                                          \
  do {                                                                             \
    _Pragma("unroll") for (int q = 0; q < 2; ++q)                                  \
        gld16(A + (size_t)(m0 + aRow[q]) * 4096 + (ks) + aCol[q],                  \
              &sA[buf][(q * 256 + tid) * 8]);                                      \
    _Pragma("unroll") for (int q = 0; q < 4; ++q)                                  \
        gld16(Bb + (size_t)bRow[q] * 4096 + (ks) + bCol[q],                        \
              &sB[buf][(q * 256 + tid) * 8]);                                      \
  } while (0)

  K2_STAGE(0, 0);
  K2_STAGE(1, 64);
  asm volatile("s_waitcnt vmcnt(6)" ::: "memory");  // tile 0's 6 loads landed
  __builtin_amdgcn_sched_barrier(0);
  __builtin_amdgcn_s_barrier();

  const int l31 = lane & 31, l15 = lane & 15, lhi = lane >> 5;
  const int nk = 64;
  for (int t = 0; t < nk; ++t) {
    const int cur = t & 1;
    const f16* pA = sA[cur];
    const f16* pB = sB[cur];
    __builtin_amdgcn_s_setprio(1);
#pragma unroll
    for (int kk = 0; kk < 4; ++kk) {
      const int c = kk * 2 + lhi;
      f16x8 af = *(const f16x8*)&pA[l31 * 128 + (((wr * 8 + c) ^ l15) * 8)];
      f16x8 b0 = *(const f16x8*)&pB[(wc * 32 + l31) * 128 + ((c ^ l15) * 8)];
      f16x8 b1 = *(const f16x8*)&pB[(wc * 32 + l31) * 128 + (((8 + c) ^ l15) * 8)];
      accN = MFMA32(af, b0, accN);
      accD = MFMA32(af, b1, accD);
    }
    __builtin_amdgcn_s_setprio(0);
    asm volatile("s_waitcnt lgkmcnt(0)" ::: "memory");
    __builtin_amdgcn_sched_barrier(0);
    __builtin_amdgcn_s_barrier();       // all waves done reading buf cur
    if (t + 2 < nk) {
      K2_STAGE(cur, (t + 2) * 64);      // DMA tile t+2 into cur
      asm volatile("s_waitcnt vmcnt(6)" ::: "memory");  // tile t+1 landed
    } else {
      asm volatile("s_waitcnt vmcnt(0)" ::: "memory");
    }
    __builtin_amdgcn_sched_barrier(0);
    __builtin_amdgcn_s_barrier();       // tile t+1 ready
  }
#undef K2_STAGE

  // fused epilogue straight from registers: Yt = sigQ * num / den
  const int h = wc * 32 + l31;
#pragma unroll
  for (int r = 0; r < 16; ++r) {
    const int trow = m0 + wr * 32 + (r & 3) + 8 * (r >> 2) + 4 * lhi;
    const size_t mrow = (size_t)b * 4096 + trow;
    const float sq = (float)sigQ[mrow * 64 + h];
    Yt[mrow * 64 + h] = (f16)(sq * accN[r] / accD[r]);
  }
}

// ---------------- k4_out: out[m][d] = Yt @ wp^T + bp (f32 out) ----------------
__global__ __launch_bounds__(256) void k4_out(const f16* __restrict__ Yt,
                                              const f16* __restrict__ wpb,
                                              const float* __restrict__ bp,
                                              float* __restrict__ out) {
  __shared__ alignas(16) f16 sA[128 * 64];
  __shared__ alignas(16) f16 sB[128 * 64];
  const int tid = threadIdx.x;
  const int wave = tid >> 6, lane = tid & 63;
  const int m0 = blockIdx.x * 128;  // 256
  const int n0 = blockIdx.y * 128;  // 4
  const int wm = (wave >> 1) * 64;
  const int wn = (wave & 1) * 64;
  const int l15 = lane & 15;
  const int sc8 = tid & 7;
  const int scol = (sc8 ^ ((tid >> 3) & 7)) * 8;

#pragma unroll
  for (int q = 0; q < 4; ++q) {
    int r = q * 32 + (tid >> 3);
    gld16(Yt + (size_t)(m0 + r) * 64 + scol, &sA[r * 64 + sc8 * 8]);
    gld16(wpb + (size_t)(n0 + r) * 64 + scol, &sB[r * 64 + sc8 * 8]);
  }
  __syncthreads();

  f32x4 acc[4][4];
#pragma unroll
  for (int i = 0; i < 4; ++i)
#pragma unroll
    for (int j = 0; j < 4; ++j) acc[i][j] = (f32x4){0.f, 0.f, 0.f, 0.f};

#pragma unroll
  for (int kk = 0; kk < 2; ++kk) {
    const int c = kk * 4 + (lane >> 4);
    f16x8 af[4], bfr[4];
#pragma unroll
    for (int i = 0; i < 4; ++i) {
      const int r = wm + i * 16 + l15;
      af[i] = *(const f16x8*)&sA[r * 64 + ((c ^ (r & 7)) * 8)];
    }
#pragma unroll
    for (int j = 0; j < 4; ++j) {
      const int r = wn + j * 16 + l15;
      bfr[j] = *(const f16x8*)&sB[r * 64 + ((c ^ (r & 7)) * 8)];
    }
#pragma unroll
    for (int i = 0; i < 4; ++i)
#pragma unroll
      for (int j = 0; j < 4; ++j) acc[i][j] = MFMA16(af[i], bfr[j], acc[i][j]);
  }

#pragma unroll
  for (int i = 0; i < 4; ++i) {
    const int row = m0 + wm + i * 16 + (lane >> 4) * 4;
#pragma unroll
    for (int j = 0; j < 4; ++j) {
      const int col = n0 + wn + j * 16 + l15;
      const float bpv = bp[col];
#pragma unroll
      for (int r = 0; r < 4; ++r)
        out[(size_t)(row + r) * 512 + col] = acc[i][j][r] + bpv;
    }
  }
}

extern "C" void kernel_launch(void* const* d_in, const int* in_sizes, int n_in,
                              void* d_out, int out_size, void* d_ws, size_t ws_size,
                              hipStream_t stream) {
  const float* x = (const float*)d_in[0];
  const float* wq = (const float*)d_in[1];
  const float* bq = (const float*)d_in[2];
  const float* wk = (const float*)d_in[3];
  const float* bk = (const float*)d_in[4];
  const float* wv = (const float*)d_in[5];
  const float* bv = (const float*)d_in[6];
  const float* wp = (const float*)d_in[7];
  const float* bp = (const float*)d_in[8];
  const float* wbias = (const float*)d_in[9];
  float* out = (float*)d_out;

  char* ws = (char*)d_ws;
  f16* ew = (f16*)(ws);                  // 33,554,432 B
  f16* XT = (f16*)(ws + 33554432);       //  8,388,608 B
  f16* sigQ = (f16*)(ws + 41943040);     //  4,194,304 B
  f16* Yt = (f16*)(ws + 46137344);       //  4,194,304 B
  f16* wqkvb = (f16*)(ws + 50331648);    //    196,608 B
  f16* wpb = (f16*)(ws + 50528256);      //     65,536 B (end 50,593,792)

  prep_ew<<<4096, 256, 0, stream>>>(wbias, ew);
  prep_w<<<128, 256, 0, stream>>>(wq, wk, wv, wp, wqkvb, wpb);
  k1_qkv<<<512, 256, 0, stream>>>(x, wqkvb, bq, bk, bv, sigQ, XT);
  k2_big<<<512, 256, 0, stream>>>(ew, XT, sigQ, Yt);
  k4_out<<<dim3(256, 4), 256, 0, stream>>>(Yt, wpb, bp, out);
}